// Round 5
// baseline (938.141 us; speedup 1.0000x reference)
//
#include <hip/hip_runtime.h>

typedef __bf16 bf16_t;
typedef __bf16 bf16x4 __attribute__((ext_vector_type(4)));
typedef __bf16 bf16x8 __attribute__((ext_vector_type(8)));
typedef float  f32x4  __attribute__((ext_vector_type(4)));

#define HID    128
#define DIO    80
#define G4     512
#define TSTEP  512
#define BB     16
#define NBATCH 4096
#define NBLK   (NBATCH / BB)
#define HSTR   136  // LDS row stride (bf16 elems)

// Activation-domain scaling folded into the weights (preprocessing):
//   i,f,o rows scaled by -log2(e)  -> exp2(acc) = e^{-gate}
//   g rows scaled by +2*log2(e)    -> exp2(acc) = e^{2g}
// c state kept in the 2*log2(e)-scaled domain so tanh(c) = (exp2(c')-1)/(exp2(c')+1).
#define NL2E  -1.4426950408889634f
#define P2L2E  2.8853900817779268f

// Fragment layout (identical indexing for A- and B-operand of 16x16x32 bf16):
// frag tile (ntile,kt): elem[lane*8+j] = W[n=ntile*16+(lane&15)][k=kt*32+(lane>>4)*8+j]
__device__ bf16_t g_weff_frags[128 * 512];
__device__ bf16_t g_whh_frags[128 * 512];
__device__ bf16_t g_wfc_frags[20 * 512];
__device__ float  g_weff[G4 * HID];
__device__ float  g_beff[G4];
__device__ float  g_b1[G4];

// W_eff = W_hh + W_ih @ W_fc ; b_eff = b_ih + b_hh + W_ih @ b_fc ; b1 = b_ih + b_hh
// All outputs pre-scaled per-row by the activation-domain constants.
__global__ void k_weff(const float* __restrict__ W_ih, const float* __restrict__ W_hh,
                       const float* __restrict__ b_ih, const float* __restrict__ b_hh,
                       const float* __restrict__ W_fc, const float* __restrict__ b_fc) {
  int gid = blockIdx.x * blockDim.x + threadIdx.x;
  int g = gid >> 7, k = gid & 127;
  float sc = ((g >> 7) == 2) ? P2L2E : NL2E;  // gate order i,f,g,o; g-gate rows = [256,384)
  float acc = W_hh[g * HID + k];
#pragma unroll 8
  for (int d = 0; d < DIO; ++d)
    acc = fmaf(W_ih[g * DIO + d], W_fc[d * HID + k], acc);
  g_weff[g * HID + k] = acc * sc;
  if (k == 0) {
    float bb = b_ih[g] + b_hh[g];
    g_b1[g] = bb * sc;
    float be = bb;
    for (int d = 0; d < DIO; ++d) be = fmaf(W_ih[g * DIO + d], b_fc[d], be);
    g_beff[g] = be * sc;
  }
}

__global__ void k_frag(const float* __restrict__ W_hh, const float* __restrict__ W_fc) {
  int tile = blockIdx.x;  // 0..275
  int lane = threadIdx.x;
  int c = lane & 15, q = lane >> 4;
  if (tile < 128) {
    int gtile = tile >> 2, kt = tile & 3;
    int n = gtile * 16 + c;
#pragma unroll
    for (int j = 0; j < 8; ++j)
      g_weff_frags[tile * 512 + lane * 8 + j] = (bf16_t)g_weff[n * HID + kt * 32 + q * 8 + j];
  } else if (tile < 256) {
    int t2 = tile - 128;
    int gtile = t2 >> 2, kt = t2 & 3;
    int n = gtile * 16 + c;
    float sc = ((n >> 7) == 2) ? P2L2E : NL2E;
#pragma unroll
    for (int j = 0; j < 8; ++j)
      g_whh_frags[t2 * 512 + lane * 8 + j] = (bf16_t)(W_hh[n * HID + kt * 32 + q * 8 + j] * sc);
  } else {
    int t2 = tile - 256;  // 0..19 (W_fc unscaled: y output path)
    int yt = t2 >> 2, kt = t2 & 3;
    int n = yt * 16 + c;
#pragma unroll
    for (int j = 0; j < 8; ++j)
      g_wfc_frags[t2 * 512 + lane * 8 + j] = (bf16_t)W_fc[n * HID + kt * 32 + q * 8 + j];
  }
}

__device__ __forceinline__ float fexp2(float x) { return __builtin_amdgcn_exp2f(x); }
__device__ __forceinline__ float frcp(float x)  { return __builtin_amdgcn_rcpf(x); }

#define MFMA16(A, B, C) __builtin_amdgcn_mfma_f32_16x16x32_bf16((A), (B), (C), 0, 0, 0)
#define SGB(m, n) __builtin_amdgcn_sched_group_barrier((m), (n), 0)

// 256 blocks x 512 threads (8 waves -> 2 waves/SIMD). Block owns 16 batch rows for all 512 steps.
// Transposed MFMA: gates^T = W_tile(A) x h^T(B). Wave w owns hidden cols [w*16, w*16+16) of each gate.
// C-layout: col(lane&15)=batch row, row(q*4+r)=hidden unit -> LSTM update in-register.
// y-projection DEFERRED one iteration (hides post-barrier ds_read latency under register MFMAs).
// Gate chains are G-outer/kt-inner so chain G completes at MFMA #4(G+1); pointwise tiers are
// interleaved into the MFMA stream (in-order issue => static interleave = dual-pipe overlap)
// and pinned with sched_group_barrier: MFMA8,VALU8,MFMA4,VALU8,MFMA4,VALU*,DS_WRITE.
__global__ __launch_bounds__(512, 2) void k_lstm(const float* __restrict__ h0,
                                                 const float* __restrict__ b_fc,
                                                 float* __restrict__ out) {
  __shared__ __align__(16) bf16_t hbuf[2][BB * HSTR];
  const int tid = threadIdx.x;
  const int lane = tid & 63;
  const int w = tid >> 6;  // 0..7
  const int c = lane & 15, q = lane >> 4;
  const int b0 = blockIdx.x * BB;

  // stage h0 -> hbuf[0]
  for (int i = tid; i < BB * HID; i += 512) {
    int r = i >> 7, k = i & 127;
    hbuf[0][r * HSTR + k] = (bf16_t)h0[(long)(b0 + r) * HID + k];
  }

  // W_fc A-fragments: waves 0..4 own y-tile w (dio cols w*16..w*16+16)
  bf16x8 Wy[4];
  f32x4  ybias;
  if (w < 5) {
#pragma unroll
    for (int kt = 0; kt < 4; ++kt)
      Wy[kt] = *(const bf16x8*)&g_wfc_frags[(w * 4 + kt) * 512 + lane * 8];
#pragma unroll
    for (int r = 0; r < 4; ++r) ybias[r] = b_fc[w * 16 + q * 4 + r];
  }

  bf16x8 Wg[4][4];  // [gate][ktile] — register/AGPR-resident
  f32x4  bias[4];   // per-r (hidden-unit) bias, pre-scaled
  auto load_wg = [&](const bf16_t* frags, const float* bsrc) {
#pragma unroll
    for (int G = 0; G < 4; ++G) {
      int gtile = G * 8 + w;
#pragma unroll
      for (int r = 0; r < 4; ++r) bias[G][r] = bsrc[gtile * 16 + q * 4 + r];
#pragma unroll
      for (int kt = 0; kt < 4; ++kt)
        Wg[G][kt] = *(const bf16x8*)&frags[(gtile * 4 + kt) * 512 + lane * 8];
    }
  };

  f32x4 cst = (f32x4){0, 0, 0, 0};  // c state (2*log2e-scaled domain), batch row c
  bf16x8 hfA[4], hfB[4];            // ping-pong B-fragments of h (h^T)

  __syncthreads();
#pragma unroll
  for (int kt = 0; kt < 4; ++kt)
    hfA[kt] = *(const bf16x8*)&hbuf[0][c * HSTR + kt * 32 + q * 8];

  float* outp = out + (long)(b0 + c) * TSTEP * DIO + w * 16 + q * 4;  // row 0

  // persistent wave-parity priority (kept constant from r2/r3)
  if (((tid >> 6) & 1) == 0) __builtin_amdgcn_s_setprio(1);

// One recurrence iteration. CUR holds h(t-1) in registers; writes h(t) to hbuf[BUF];
// post-barrier: issue reads of h(t) into NXT, then (EMIT) y(h(t-1)) from CUR + store.
#define ITER(CUR, NXT, BUF, EMIT)                                                      \
  do {                                                                                 \
    f32x4 aI, aF, aG, aO;                                                              \
    /* i-chain: completes at MFMA #4 */                                                \
    aI = MFMA16(Wg[0][0], CUR[0], bias[0]);                                            \
    aI = MFMA16(Wg[0][1], CUR[1], aI);                                                 \
    aI = MFMA16(Wg[0][2], CUR[2], aI);                                                 \
    aI = MFMA16(Wg[0][3], CUR[3], aI);                                                 \
    /* f-chain: completes at MFMA #8 */                                                \
    aF = MFMA16(Wg[1][0], CUR[0], bias[1]);                                            \
    aF = MFMA16(Wg[1][1], CUR[1], aF);                                                 \
    aF = MFMA16(Wg[1][2], CUR[2], aF);                                                 \
    aF = MFMA16(Wg[1][3], CUR[3], aF);                                                 \
    /* tier1 VALU (needs only aI) — issues under g/o-chain MFMAs */                    \
    f32x4 Ei, ai;                                                                      \
    _Pragma("unroll")                                                                  \
    for (int r = 0; r < 4; ++r) Ei[r] = fexp2(aI[r]);                                  \
    _Pragma("unroll")                                                                  \
    for (int r = 0; r < 4; ++r) ai[r] = 1.0f + Ei[r];                                  \
    /* g-chain: completes at MFMA #12 */                                               \
    aG = MFMA16(Wg[2][0], CUR[0], bias[2]);                                            \
    aG = MFMA16(Wg[2][1], CUR[1], aG);                                                 \
    aG = MFMA16(Wg[2][2], CUR[2], aG);                                                 \
    aG = MFMA16(Wg[2][3], CUR[3], aG);                                                 \
    /* tier2 VALU (needs only aF) */                                                   \
    f32x4 Ef, af;                                                                      \
    _Pragma("unroll")                                                                  \
    for (int r = 0; r < 4; ++r) Ef[r] = fexp2(aF[r]);                                  \
    _Pragma("unroll")                                                                  \
    for (int r = 0; r < 4; ++r) af[r] = 1.0f + Ef[r];                                  \
    /* o-chain: completes at MFMA #16 */                                               \
    aO = MFMA16(Wg[3][0], CUR[0], bias[3]);                                            \
    aO = MFMA16(Wg[3][1], CUR[1], aO);                                                 \
    aO = MFMA16(Wg[3][2], CUR[2], aO);                                                 \
    aO = MFMA16(Wg[3][3], CUR[3], aO);                                                 \
    /* tail pointwise (identical math/order to r3 version) */                          \
    bf16x4 hv;                                                                         \
    _Pragma("unroll")                                                                  \
    for (int r = 0; r < 4; ++r) {                                                      \
      float Eg = fexp2(aG[r]); /* e^2g */                                              \
      float ag = 1.0f + Eg;                                                            \
      float P1 = ai[r] * ag;                                                           \
      float R  = frcp(P1 * af[r]);                                                     \
      float tg = __builtin_fmaf(Eg, P2L2E, -P2L2E); /* 2L*(Eg-1) */                    \
      float m2 = tg * af[r];                                                           \
      float u  = __builtin_fmaf(P1, cst[r], m2);                                       \
      float cn = u * R; /* = sig(f)*c + 2L*sig(i)*tanh(g) */                           \
      cst[r] = cn;                                                                     \
      float cc = fminf(cn, 80.0f); /* exp2 overflow guard */                           \
      float Ec = fexp2(cc);        /* e^2c */                                          \
      float Eo = fexp2(aO[r]);     /* e^-o */                                          \
      float R2 = frcp((1.0f + Eo) * (1.0f + Ec));                                      \
      hv[r] = (bf16_t)((Ec - 1.0f) * R2); /* sig(o)*tanh(c) */                         \
    }                                                                                  \
    *(bf16x4*)&hbuf[BUF][c * HSTR + w * 16 + q * 4] = hv;                              \
    /* pin the interleave: in-order issue => MFMA groups host the VALU tiers */        \
    SGB(0x008, 8);   /* i+f chains */                                                  \
    SGB(0x002, 8);   /* tier1: Ei, ai */                                               \
    SGB(0x008, 4);   /* g chain */                                                     \
    SGB(0x002, 8);   /* tier2: Ef, af */                                               \
    SGB(0x008, 4);   /* o chain */                                                     \
    SGB(0x002, 128); /* tail pointwise + pack */                                       \
    SGB(0x200, 1);   /* ds_write of h */                                               \
    __syncthreads();                                                                   \
    _Pragma("unroll")                                                                  \
    for (int kt = 0; kt < 4; ++kt)                                                     \
      NXT[kt] = *(const bf16x8*)&hbuf[BUF][c * HSTR + kt * 32 + q * 8];                \
    if (EMIT && w < 5) { /* y from CUR (register-resident, no wait) fills read latency */ \
      f32x4 ya = MFMA16(Wy[0], CUR[0], ybias);                                         \
      ya = MFMA16(Wy[1], CUR[1], ya);                                                  \
      ya = MFMA16(Wy[2], CUR[2], ya);                                                  \
      ya = MFMA16(Wy[3], CUR[3], ya);                                                  \
      *(f32x4*)outp = ya;                                                              \
      outp += DIO;                                                                     \
    }                                                                                  \
  } while (0)

  // iter 1: x0 == 0 => gates = h0 @ W_hh^T + (b_ih + b_hh); no y emitted yet
  load_wg(g_whh_frags, g_b1);
  ITER(hfA, hfB, 1, false);
  // iters 2..512: fused recurrence (x eliminated: W_eff = W_hh + W_ih@W_fc)
  load_wg(g_weff_frags, g_beff);
  // pairs (2,3),(4,5),...,(510,511): even iter cur=hfB buf0, odd iter cur=hfA buf1
  for (int p = 0; p < 255; ++p) {
    ITER(hfB, hfA, 0, true);
    ITER(hfA, hfB, 1, true);
  }
  ITER(hfB, hfA, 0, true);  // iter 512: emits y(h511), loads h512 -> hfA

  // epilogue: y(h512) -> row 511
  if (w < 5) {
    f32x4 ya = MFMA16(Wy[0], hfA[0], ybias);
    ya = MFMA16(Wy[1], hfA[1], ya);
    ya = MFMA16(Wy[2], hfA[2], ya);
    ya = MFMA16(Wy[3], hfA[3], ya);
    *(f32x4*)outp = ya;
  }
#undef ITER
}

extern "C" void kernel_launch(void* const* d_in, const int* in_sizes, int n_in,
                              void* d_out, int out_size, void* d_ws, size_t ws_size,
                              hipStream_t stream) {
  const float* h0   = (const float*)d_in[0];
  const float* W_ih = (const float*)d_in[1];
  const float* W_hh = (const float*)d_in[2];
  const float* b_ih = (const float*)d_in[3];
  const float* b_hh = (const float*)d_in[4];
  const float* W_fc = (const float*)d_in[5];
  const float* b_fc = (const float*)d_in[6];
  float* out = (float*)d_out;

  k_weff<<<256, 256, 0, stream>>>(W_ih, W_hh, b_ih, b_hh, W_fc, b_fc);
  k_frag<<<276, 64, 0, stream>>>(W_hh, W_fc);
  k_lstm<<<NBLK, 512, 0, stream>>>(h0, b_fc, out);
}